// Round 18
// baseline (142.287 us; speedup 1.0000x reference)
//
#include <hip/hip_runtime.h>
#include <math.h>

typedef _Float16 half_t;
typedef _Float16 half8 __attribute__((ext_vector_type(8)));
typedef _Float16 half4 __attribute__((ext_vector_type(4)));
typedef _Float16 half2v __attribute__((ext_vector_type(2)));
typedef float f32x2 __attribute__((ext_vector_type(2)));
typedef float f32x4 __attribute__((ext_vector_type(4)));
typedef float f32x16 __attribute__((ext_vector_type(16)));
typedef unsigned int uint4v __attribute__((ext_vector_type(4)));

#define MFMA_S(a, b, c) __builtin_amdgcn_mfma_f32_32x32x16_f16((a), (b), (c), 0, 0, 0)

static constexpr int kM  = 512;
static constexpr int kD  = 64;
static constexpr int kKL = 2560;
static constexpr int kL  = 2048;
// ws (halves): Kh f16 [bh][2560][64] | Vc chunked [bh][80][64][32] | peT [l][d]
static constexpr int WS_KH  = 0;                    // 5,242,880
static constexpr int WS_VC  = 5242880;              // 5,242,880
static constexpr int WS_PET = WS_VC + 5242880;      // 131,072
// byte offsets past the half region (10,616,832 halves = 21,233,664 B):
static constexpr size_t WS_ZP_B = 21233664;         // zp f32 [4][16384]   (256 KB)
static constexpr size_t WS_PO_B = WS_ZP_B + 262144; // po f32 [4][16384][64] (16 MB)

// ---------- K1a: K convert f32->f16 (RNE, same as old commitK path) ----------
__global__ __launch_bounds__(256) void prep_kc(const float* __restrict__ k,
    half_t* __restrict__ ws) {
  const int i = blockIdx.x * 256 + threadIdx.x;     // 655,360 x 8 elems
  const float* src = k + (size_t)i * 8;
  half_t* dst = ws + WS_KH + (size_t)i * 8;
  const float4 a = ((const float4*)src)[0];
  const float4 b = ((const float4*)src)[1];
  half_t tt[8];
  tt[0] = (half_t)a.x; tt[1] = (half_t)a.y; tt[2] = (half_t)a.z; tt[3] = (half_t)a.w;
  tt[4] = (half_t)b.x; tt[5] = (half_t)b.y; tt[6] = (half_t)b.z; tt[7] = (half_t)b.w;
  *(int4*)dst = *(int4*)tt;
}

// ---------- K1b: V chunked-transpose + pe transpose ----------
__global__ __launch_bounds__(256) void prep_tr(const float* __restrict__ v,
    const float* __restrict__ pe, half_t* __restrict__ ws) {
  __shared__ float ls[64 * 72];
  const int b = blockIdx.x, t = threadIdx.x;   // grid 1312: 1280 V + 32 pe
  const bool isV = (b < 1280);
  int bh = 0, kt = 0, b3 = 0;
  const float* src; int sstride;
  if (isV) {
    bh = b / 40; kt = b % 40;
    src = v + (size_t)(bh * 2560 + kt * 64) * 64; sstride = 64;
  } else {
    b3 = b - 1280;
    src = pe + (size_t)b3 * 64; sstride = 2048;
  }
  const int rr = t >> 4, cq = (t & 15) * 4;
#pragma unroll
  for (int p = 0; p < 4; ++p) {
    const float4 x = *(const float4*)(src + (size_t)(p * 16 + rr) * sstride + cq);
    *(float4*)(ls + (p * 16 + rr) * 72 + cq) = x;
  }
  __syncthreads();
  const int oc = t >> 2, ch = t & 3;
  half_t tmp[16];
#pragma unroll
  for (int i2 = 0; i2 < 16; ++i2) tmp[i2] = (half_t)ls[(ch * 16 + i2) * 72 + oc];
  half_t* o;
  if (isV) {
    o = ws + WS_VC + (size_t)bh * 163840 + ((kt << 1) + (ch >> 1)) * 2048 + oc * 32 + ((ch & 1) << 4);
  } else {
    o = ws + WS_PET + ((size_t)b3 * 64 + oc) * 64 + ch * 16;
  }
  ((int4*)o)[0] = ((int4*)tmp)[0];
  ((int4*)o)[1] = ((int4*)tmp)[1];
}

// ---------- K2: 32x32-MFMA split-K attention, BARRIER-FREE main loop ----------
// grid 512 = 32bh x 4 m-blocks x 4 K-splits (17 chunks). 4 waves/block.
// R35 vs R12 (44.2us best): __syncthreads emits s_waitcnt vmcnt(0) before
// s_barrier (guide: barrier drain) -> every per-step barrier FORCE-DRAINED all
// in-flight prefetches. Explains R1 (occupancy null: all waves drain at own
// barriers), R17 (prefetch-distance null: drained same step regardless), and
// the ~6Kcy step window vs ~1Kcy work. Fix: remove ALL in-loop barriers by
// removing inter-wave sharing — each wave loads its own K/V/pet frags direct
// from global into regs (L2-resident: per-XCD working set ~4MB; K f16 via new
// prep_kc). Em ring stays wave-private LDS (program-order safe). Prefetches
// issued at step t now survive into t+1; 2 waves/SIMD slide freely. One
// barrier remains (pre-epilogue LDS overlay). Numerics bit-identical to R12.
// Layouts (32x32x16): A[m=lane&31][k=8*(lane>>5)+j]; B[k=8*(lane>>5)+j][n=lane&31];
// C: col=lane&31, row=(reg&3)+8*(reg>>2)+4*(lane>>5).
// Em ring f32 (64, pos=(l+qm)&63): b32 writes conflict-free; b64 reads no-wrap.
// LDS: Em-f32 4x8448 = 33,792 B (+1KB epilogue overlay slack) = 34,816 B.
__global__ __launch_bounds__(256, 2) void attn_kernel(
    const float* __restrict__ qg, const half_t* __restrict__ ws,
    const float* __restrict__ cvp, float* __restrict__ po,
    float* __restrict__ zp) {

  __shared__ __align__(16) char smem[34816];

  const int tid  = threadIdx.x;
  const int lane = tid & 63;
  const int w    = tid >> 6;                    // wave 0..3
  const int c32  = lane & 31;                   // MFMA col (query m / key / d)
  const int h    = lane >> 5;                   // half-wave

  const int id = blockIdx.x;                    // 512
  const int bh = ((id & 7) << 2) | (id >> 7);   // XCD-aware
  const int mid = (id >> 3) & 15;
  const int mb = mid & 3, sp = mid >> 2;
  const int m0 = mb << 7;                       // 128 rows per block
  const int g0 = sp * 17;                       // chunks [g0, g0+17)

  const float cvl = cvp[bh & 7] * 2048.0f - 2047.0f;  // mask = clamp((l+cvl)/64+1,0,1)
  const float cvO = cvl * 0.015625f + 1.0f;

  const half_t* khb = ws + WS_KH + (size_t)bh * (kKL * kD);
  const half_t* vcb = ws + WS_VC + (size_t)bh * (kKL * kD);
  const half_t* pet = ws + WS_PET;

  // Q B-frags from f32, scaled: B[k=d=16t+8h+j][n=m=c32], t=0..3
  const float QS = 0.125f * 1.4426950408889634f;      // 1/sqrt(64) * log2(e)
  const float* qrowF = qg + (size_t)(bh * kM + m0 + 32 * w + c32) * kD;
  half8 bq[4];
#pragma unroll
  for (int t = 0; t < 4; ++t) {
    const float4 qa = *(const float4*)(qrowF + t * 16 + h * 8);
    const float4 qb = *(const float4*)(qrowF + t * 16 + h * 8 + 4);
    bq[t] = half8{ (half_t)(qa.x * QS), (half_t)(qa.y * QS),
                   (half_t)(qa.z * QS), (half_t)(qa.w * QS),
                   (half_t)(qb.x * QS), (half_t)(qb.y * QS),
                   (half_t)(qb.z * QS), (half_t)(qb.w * QS) };
  }

  // Em f32 strip: wave w region 2112 f32; row qm stride 66
  float* stfF = (float*)smem + w * 2112 + c32 * 66;

  // K A-frags direct from global f16: A[m=key=c32][k=16kt+8h+j]
  auto loadK = [&](int gg, half8* ak) {
    const half_t* kp = khb + (size_t)(m0 + (gg << 5) + c32) * kD + h * 8;
#pragma unroll
    for (int kt = 0; kt < 4; ++kt) ak[kt] = *(const half8*)(kp + kt * 16);
  };
  // V^T A-frags direct from global (Vc layout: frag = 16B contiguous)
  auto loadV = [&](int gg, half8* vf) {
    const half_t* vp = vcb + (size_t)((m0 >> 5) + gg) * 2048 + h * 8;
#pragma unroll
    for (int dh = 0; dh < 2; ++dh)
#pragma unroll
      for (int kt = 0; kt < 2; ++kt)
        vf[dh * 2 + kt] = *(const half8*)(vp + (32 * dh + c32) * 32 + kt * 16);
  };
  // pet gather for PE window [wb, wb+32) (divergent rows, clamped)
  auto petL = [&](int wb, half8* p) {
    int l = wb + c32; l = l < 0 ? 0 : (l > kL - 1 ? kL - 1 : l);
    const half_t* pp = pet + (size_t)l * kD;
#pragma unroll
    for (int t = 0; t < 4; ++t) p[t] = *(const half8*)(pp + t * 16 + h * 8);
  };
  auto peMFMA = [&](const half8* p) -> f32x16 {
    f32x16 a = {};
#pragma unroll
    for (int t = 0; t < 4; ++t) a = MFMA_S(p[t], bq[t], a);
    return a;
  };
  // Store bias' = pe_bias + log2(mask) as F32 (-inf == masked out).
  auto stripWrite = [&](int wb, const f32x16& a) {
    const int allone  = (wb >= 0) && (wb + 31 <= kL - 1) && (wb + cvl >= 0.0f);
    const int allzero = (wb > kL - 1) || (wb + 31 < 0) || ((float)(wb + 31) + cvl <= -64.0f);
#pragma unroll
    for (int reg = 0; reg < 16; ++reg) {
      const int lr = (reg & 3) + 8 * (reg >> 2) + 4 * h;
      const int l  = wb + lr;
      float bl;
      if (allzero) bl = -HUGE_VALF;
      else if (allone) bl = a[reg];
      else {
        const float mk = fminf(fmaxf((float)l * 0.015625f + cvO, 0.0f), 1.0f);
        const float lg = __builtin_amdgcn_logf(mk);   // v_log_f32: log2; log2(0) = -inf
        bl = ((unsigned)l < (unsigned)kL) ? a[reg] + lg : -HUGE_VALF;
      }
      stfF[(l + c32) & 63] = bl;
    }
  };

  float zmc = 0.0f;
  f32x16 o0 = {}, o1 = {};                      // O^T d in [0,32) / [32,64)

  // One 32-key step: K/V frags from registers, Em window [B,B+32) from LDS.
  auto doStep = [&](int B, const half8* ak, const half8* vf) {
    // ---- S accumulator C-INIT from f32 Em ring (chain head) ----
    f32x16 s;
#pragma unroll
    for (int q = 0; q < 4; ++q) {
      const int base = (B + 8 * q + 4 * h) & 63;
      const f32x2 lo = *(const f32x2*)(stfF + base);
      const f32x2 hi = *(const f32x2*)(stfF + base + 2);
      s[4 * q + 0] = lo.x; s[4 * q + 1] = lo.y;
      s[4 * q + 2] = hi.x; s[4 * q + 3] = hi.y;
    }

    // ---- S^T = K.Q^T + bias' (C-init) ----
#pragma unroll
    for (int kt = 0; kt < 4; ++kt) s = MFMA_S(ak[kt], bq[kt], s);

    // ---- softmax: pm = exp2(s); zmc tree-sum; pack via cvt_pkrtz ----
    float pm[16];
#pragma unroll
    for (int reg = 0; reg < 16; ++reg) pm[reg] = __builtin_amdgcn_exp2f(s[reg]);
    {
      const float t0 = (pm[0] + pm[1]) + (pm[2] + pm[3]);
      const float t1 = (pm[4] + pm[5]) + (pm[6] + pm[7]);
      const float t2 = (pm[8] + pm[9]) + (pm[10] + pm[11]);
      const float t3 = (pm[12] + pm[13]) + (pm[14] + pm[15]);
      zmc += (t0 + t1) + (t2 + t3);
    }
    unsigned Wp[8];
#pragma unroll
    for (int q = 0; q < 8; ++q)
      Wp[q] = __builtin_bit_cast(unsigned,
                __builtin_amdgcn_cvt_pkrtz(pm[2 * q], pm[2 * q + 1]));
    // C->B refragmentation in-register: half-wave exchange.
    const auto r0 = __builtin_amdgcn_permlane32_swap(Wp[0], Wp[2], false, false);
    const auto r1 = __builtin_amdgcn_permlane32_swap(Wp[1], Wp[3], false, false);
    const auto r2 = __builtin_amdgcn_permlane32_swap(Wp[4], Wp[6], false, false);
    const auto r3 = __builtin_amdgcn_permlane32_swap(Wp[5], Wp[7], false, false);
    const uint4v u0 = { (unsigned)r0[0], (unsigned)r1[0], (unsigned)r0[1], (unsigned)r1[1] };
    const uint4v u1 = { (unsigned)r2[0], (unsigned)r3[0], (unsigned)r2[1], (unsigned)r3[1] };
    const half8 pb0 = __builtin_bit_cast(half8, u0);   // B[k=8h+j][m], keys 0..15
    const half8 pb1 = __builtin_bit_cast(half8, u1);   // keys 16..31

    // ---- PV: O^T[d][m] += V^T.P ----
    o0 = MFMA_S(vf[0], pb0, o0);
    o0 = MFMA_S(vf[1], pb1, o0);
    o1 = MFMA_S(vf[2], pb0, o1);
    o1 = MFMA_S(vf[3], pb1, o1);
  };

  // ---- prologue (all wave-private; no barrier) ----
  half8 akA[4], akB[4], vfA[4], vfB[4], ppA[4], ppB[4];
  const int B0 = (g0 << 5) - 32 * w;
  loadK(g0, akA); loadV(g0, vfA);
  {
    half8 pq[4];
    petL(B0 - 32, pq); stripWrite(B0 - 32, peMFMA(pq));
    petL(B0,      pq); stripWrite(B0,      peMFMA(pq));
  }
  petL(B0 + 32, ppA);                           // step 0 tail window

  for (int p = 0; p < 8; ++p) {
    const int g = g0 + 2 * p;
    const int B = (g << 5) - 32 * w;

    // ---- even step t=2p (set A) ----
    loadK(g + 1, akB); loadV(g + 1, vfB);       // frags for step t+1
    petL(B + 64, ppB);                          // window for step t+1 tail
    doStep(B, akA, vfA);
    stripWrite(B + 32, peMFMA(ppA));            // window for step t+1
    // ---- odd step t+1 (set B) ----
    const int B2 = B + 32;
    loadK(g + 2, akA); loadV(g + 2, vfA);       // frags for step t+2 (p=7: chunk g0+16)
    if (p < 7) petL(B2 + 64, ppA);              // window for step t+2 tail
    doStep(B2, akB, vfB);
    stripWrite(B2 + 32, peMFMA(ppB));           // window for step t+2
  }
  doStep(((g0 + 16) << 5) - 32 * w, akA, vfA);  // tail step 16 (no produce)

  // ---- epilogue: plain partial stores (no atomics) ----
  __syncthreads();                              // sole block barrier: fence Em strips before overlay
  float* Ow = (float*)smem + (size_t)w * 2176;  // [32 m][stride 68] f32, wave-local
#pragma unroll
  for (int q = 0; q < 4; ++q) {
    *(f32x4*)(Ow + c32 * 68 + 0  + 8 * q + 4 * h) =
        f32x4{o0[q * 4], o0[q * 4 + 1], o0[q * 4 + 2], o0[q * 4 + 3]};
    *(f32x4*)(Ow + c32 * 68 + 32 + 8 * q + 4 * h) =
        f32x4{o1[q * 4], o1[q * 4 + 1], o1[q * 4 + 2], o1[q * 4 + 3]};
  }
  zmc += __shfl_xor(zmc, 32);
  const int rowbase = bh * kM + m0 + 32 * w;
  if (lane < 32) zp[(size_t)sp * 16384 + rowbase + c32] = zmc;
  __syncthreads();
  float* pob = po + ((size_t)sp * 16384 + rowbase) * 64;
#pragma unroll
  for (int u = 0; u < 8; ++u) {
    const int row = u * 4 + (lane >> 4);        // wave-local row 0..31
    const int d4 = (lane & 15) << 2;
    *(f32x4*)(pob + (size_t)row * 64 + d4) = *(const f32x4*)(Ow + row * 68 + d4);
  }
}

// ---------- K3: 4-way split reduce + normalize ----------
__global__ __launch_bounds__(256) void norm_kernel(const float* __restrict__ zp,
    const float* __restrict__ po, float* __restrict__ out) {
  const int i = blockIdx.x * 256 + threadIdx.x;   // 262,144
  const int row = i >> 4, d4 = (i & 15) << 2;
  const float z = zp[row] + zp[16384 + row] + zp[32768 + row] + zp[49152 + row];
  const float inv = 1.0f / (z + 1e-20f);
  f32x4 a = *(const f32x4*)(po + (size_t)row * 64 + d4);
  const f32x4 b = *(const f32x4*)(po + 1048576u + (size_t)row * 64 + d4);
  const f32x4 c = *(const f32x4*)(po + 2097152u + (size_t)row * 64 + d4);
  const f32x4 d = *(const f32x4*)(po + 3145728u + (size_t)row * 64 + d4);
  a = a + b + c + d;
  *(f32x4*)(out + (size_t)row * 64 + d4) = a * inv;
}

extern "C" void kernel_launch(void* const* d_in, const int* in_sizes, int n_in,
                              void* d_out, int out_size, void* d_ws, size_t ws_size,
                              hipStream_t stream) {
  (void)in_sizes; (void)n_in; (void)out_size; (void)ws_size;
  const float* q  = (const float*)d_in[0];
  const float* k  = (const float*)d_in[1];
  const float* v  = (const float*)d_in[2];
  const float* pe = (const float*)d_in[3];
  const float* cv = (const float*)d_in[4];
  half_t* ws = (half_t*)d_ws;   // needs ~37.5 MB
  float* out = (float*)d_out;
  float* zp = (float*)((char*)d_ws + WS_ZP_B);
  float* po = (float*)((char*)d_ws + WS_PO_B);

  prep_kc<<<2560, 256, 0, stream>>>(k, ws);
  prep_tr<<<1312, 256, 0, stream>>>(v, pe, ws);
  attn_kernel<<<512, 256, 0, stream>>>(q, ws, cv, po, zp);
  norm_kernel<<<1024, 256, 0, stream>>>(zp, po, out);
}